// Round 5
// baseline (517.653 us; speedup 1.0000x reference)
//
#include <hip/hip_runtime.h>
#include <stdint.h>

#define BDIM 32
#define CDIM 32
#define LDIM 1024
#define VDIM 4096
#define BCL (BDIM*CDIM*LDIM)
#define LT 64    // fuse l-tile
#define TR 256   // vq emb rows per LDS tile
#define NQTOT 43680  // 32 * (1+4+16+64+256+1024)

// ---------------------------------------------------------------- helpers
__device__ __forceinline__ unsigned ord_enc(float m) {
    unsigned u = __float_as_uint(m);
    return ((int)u >= 0) ? (u | 0x80000000u) : ~u;
}

// ---------------------------------------------------------------- init
__global__ void init_kernel(const float* __restrict__ emb, const float* __restrict__ phiw,
                            float* __restrict__ e_sq, float* __restrict__ w_t,
                            unsigned long long* __restrict__ keys,
                            float* __restrict__ loss_acc) {
    int i = blockIdx.x * blockDim.x + threadIdx.x;
    if (i < VDIM) {
        const float4* e4 = (const float4*)(emb + (size_t)i * CDIM);
        float s = 0.f;
#pragma unroll
        for (int k = 0; k < 8; ++k) {
            float4 v = e4[k];
            s += v.x*v.x; s += v.y*v.y; s += v.z*v.z; s += v.w*v.w;
        }
        e_sq[i] = s;
    }
    if (i < 4 * 96 * 32) {
        int p  = i / 3072;
        int r  = i - p * 3072;
        int ik = r >> 5;
        int o  = r & 31;
        w_t[i] = phiw[p * 3072 + o * 96 + ik];   // [p][ik][o] <- [p][o][ik]
    }
    if (i < NQTOT) keys[i] = 0ull;
    if (i == 0) *loss_acc = 0.f;
}

// ---------------------------------------------------------------- VQ
// lane holds QPL queries in VGPRs; broadcast LDS row-reads amortized over
// QPL*4 FMAs. argmin d == argmax m = dot - e^2/2. atomicMax on
// (ord(m)<<32)|~idx -> ties resolve to smallest idx.
// __launch_bounds__(256,2): VGPR cap 256 so z[QPL][32] stays in VGPRs
// (round-4 lesson: default heuristic chose 84 VGPRs and AGPR-spilled z,
// costing 2.4x VALU issue).
__device__ __forceinline__ void load_z(const float* __restrict__ fr, int q, int lpl,
                                       float* z) {
    int b = q >> lpl;
    int j = q & ((1 << lpl) - 1);
    if (lpl == 10) {
        const float* base = fr + b * (CDIM * LDIM) + j;
#pragma unroll
        for (int c = 0; c < 32; ++c) z[c] = base[c << 10];
    } else {
        int sh = 10 - lpl;
        int col = (j << sh) + (1 << (sh - 1)) - 1;
        const float* base = fr + b * (CDIM * LDIM) + col;
#pragma unroll
        for (int c = 0; c < 32; ++c)
            z[c] = 0.5f * (base[c << 10] + base[(c << 10) + 1]);
    }
}

template<int QPL>
__global__ __launch_bounds__(256, 2) void vq_kernel(
    const float* __restrict__ src, const float* __restrict__ emb,
    const float* __restrict__ e_sq, unsigned long long* __restrict__ keys,
    int lpl, int NQ, int vsplit, int CR)
{
    const int t  = threadIdx.x;
    const int qb = blockIdx.x / vsplit;
    const int vc = blockIdx.x - qb * vsplit;

    __shared__ float4 et[TR * 8];
    __shared__ float  es2[TR];      // -e_sq/2

    float z[QPL][32];
    int   q[QPL];
#pragma unroll
    for (int k = 0; k < QPL; ++k) {
        q[k] = qb * (256 * QPL) + k * 256 + t;
        load_z(src, min(q[k], NQ - 1), lpl, z[k]);
    }

    float bm[QPL]; int bv[QPL];
#pragma unroll
    for (int k = 0; k < QPL; ++k) { bm[k] = -3.4e38f; bv[k] = 0; }

    const int vbase = vc * CR;
    for (int tb = 0; tb < CR; tb += TR) {
        const int rows = min(TR, CR - tb);
        const float4* g = (const float4*)(emb + (size_t)(vbase + tb) * CDIM);
        for (int x = t; x < rows * 8; x += 256) et[x] = g[x];
        for (int x = t; x < rows;     x += 256) es2[x] = -0.5f * e_sq[vbase + tb + x];
        __syncthreads();

        for (int r = 0; r < rows; r += 2) {
            float es0 = es2[r], es1 = es2[r + 1];
            float m0[QPL], m1[QPL];
#pragma unroll
            for (int k = 0; k < QPL; ++k) { m0[k] = es0; m1[k] = es1; }
#pragma unroll
            for (int c4 = 0; c4 < 8; ++c4) {
                float4 e0 = et[(r + 0) * 8 + c4];   // broadcast
                float4 e1 = et[(r + 1) * 8 + c4];
#pragma unroll
                for (int k = 0; k < QPL; ++k) {
                    m0[k] = fmaf(e0.x, z[k][4*c4+0], m0[k]);
                    m0[k] = fmaf(e0.y, z[k][4*c4+1], m0[k]);
                    m0[k] = fmaf(e0.z, z[k][4*c4+2], m0[k]);
                    m0[k] = fmaf(e0.w, z[k][4*c4+3], m0[k]);
                    m1[k] = fmaf(e1.x, z[k][4*c4+0], m1[k]);
                    m1[k] = fmaf(e1.y, z[k][4*c4+1], m1[k]);
                    m1[k] = fmaf(e1.z, z[k][4*c4+2], m1[k]);
                    m1[k] = fmaf(e1.w, z[k][4*c4+3], m1[k]);
                }
            }
            int vr = vbase + tb + r;
#pragma unroll
            for (int k = 0; k < QPL; ++k) {
                if (m0[k] > bm[k]) { bm[k] = m0[k]; bv[k] = vr; }
                if (m1[k] > bm[k]) { bm[k] = m1[k]; bv[k] = vr + 1; }
            }
        }
        __syncthreads();
    }

#pragma unroll
    for (int k = 0; k < QPL; ++k) {
        if (q[k] < NQ) {
            unsigned long long key =
                ((unsigned long long)ord_enc(bm[k]) << 32) | (unsigned)(~bv[k]);
            atomicMax(&keys[q[k]], key);
        }
    }
}

// ---------------------------------------------------------------- fused gather+upsample+phi+update+loss
__global__ __launch_bounds__(256) void fuse_kernel(
    const float* __restrict__ f, const float* __restrict__ emb,
    const unsigned long long* __restrict__ keys,
    const float* __restrict__ w_t, const float* __restrict__ bias,
    float* __restrict__ f_rest, float* __restrict__ f_hat,
    float* __restrict__ loss_acc, int lpl, int first, int last)
{
    const int t  = threadIdx.x;
    const int b  = blockIdx.y;
    const int l0 = blockIdx.x * LT;

    __shared__ float w_s[96 * 32];       // [ik][o]
    __shared__ float b_s[32];
    __shared__ float hs[32 * 68];        // [i][66 cols + pad]
    __shared__ float red[4];

    {
        const float4* w4 = (const float4*)w_t;
        float4* s4 = (float4*)w_s;
        for (int x = t; x < 768; x += 256) s4[x] = w4[x];
    }
    if (t < 32) b_s[t] = bias[t];

    {
        const int col  = t >> 1;
        const int half = t & 1;
        if (col < LT + 2) {
            int l = l0 - 1 + col;
            if (l < 0 || l >= LDIM) {
#pragma unroll
                for (int i4 = 0; i4 < 4; ++i4) {
                    int i = (half * 4 + i4) * 4;
                    hs[(i+0) * 68 + col] = 0.f;
                    hs[(i+1) * 68 + col] = 0.f;
                    hs[(i+2) * 68 + col] = 0.f;
                    hs[(i+3) * 68 + col] = 0.f;
                }
            } else {
                int pl = 1 << lpl;
                int lo, hi; float wg;
                if (lpl == 10) { lo = l; hi = l; wg = 0.f; }
                else {
                    float pos = (l + 0.5f) * ((float)pl / 1024.0f) - 0.5f;
                    pos = fminf(fmaxf(pos, 0.f), (float)(pl - 1));
                    lo = (int)floorf(pos);
                    hi = min(lo + 1, pl - 1);
                    wg = pos - (float)lo;
                }
                int v0 = ~(unsigned)(keys[b * pl + lo]);
                int v1 = ~(unsigned)(keys[b * pl + hi]);
                const float4* e0 = (const float4*)(emb + (size_t)v0 * 32) + half * 4;
                const float4* e1 = (const float4*)(emb + (size_t)v1 * 32) + half * 4;
                float om = 1.0f - wg;
#pragma unroll
                for (int i4 = 0; i4 < 4; ++i4) {
                    float4 a = e0[i4]; float4 c = e1[i4];
                    int i = (half * 4 + i4) * 4;
                    hs[(i+0) * 68 + col] = a.x * om + c.x * wg;
                    hs[(i+1) * 68 + col] = a.y * om + c.y * wg;
                    hs[(i+2) * 68 + col] = a.z * om + c.z * wg;
                    hs[(i+3) * 68 + col] = a.w * om + c.w * wg;
                }
            }
        }
    }
    __syncthreads();

    const int o   = t >> 3;
    const int sub = t & 7;
    float acc[8];
#pragma unroll
    for (int u = 0; u < 8; ++u) acc[u] = 0.f;
    const int hbase = sub * 8;           // float4-aligned (68 = 4*17)

    for (int i = 0; i < 32; ++i) {
        float w0 = w_s[(i * 3 + 0) * 32 + o];
        float w1 = w_s[(i * 3 + 1) * 32 + o];
        float w2 = w_s[(i * 3 + 2) * 32 + o];
        const float4* hr4 = (const float4*)&hs[i * 68 + hbase];
        float4 ha = hr4[0], hb = hr4[1], hc = hr4[2];   // 12 floats, use 10
        float hw[10] = {ha.x, ha.y, ha.z, ha.w, hb.x, hb.y, hb.z, hb.w, hc.x, hc.y};
#pragma unroll
        for (int u = 0; u < 8; ++u) {
            acc[u] = fmaf(w0, hw[u],     acc[u]);
            acc[u] = fmaf(w1, hw[u + 1], acc[u]);
            acc[u] = fmaf(w2, hw[u + 2], acc[u]);
        }
    }

    const int gbase = (b * 32 + o) * LDIM + l0 + sub * 8;
    float ph[8];
#pragma unroll
    for (int u = 0; u < 8; ++u) {
        float hval = hs[o * 68 + sub * 8 + 1 + u];
        ph[u] = 0.5f * hval + 0.5f * (acc[u] + b_s[o]);   // RESI = 0.5
    }

    const float4* fp  = (const float4*)(f + gbase);
    float4*       fhp = (float4*)(f_hat + gbase);
    float4*       frp = (float4*)(f_rest + gbase);
    float4 fa = fp[0], fb = fp[1];
    float4 h0, h1;
    if (first) { h0 = make_float4(0,0,0,0); h1 = make_float4(0,0,0,0); }
    else       { h0 = fhp[0]; h1 = fhp[1]; }
    h0.x += ph[0]; h0.y += ph[1]; h0.z += ph[2]; h0.w += ph[3];
    h1.x += ph[4]; h1.y += ph[5]; h1.z += ph[6]; h1.w += ph[7];
    fhp[0] = h0; fhp[1] = h1;

    if (!last) {
        float4 r0, r1;
        if (first) {
            r0 = make_float4(fa.x - ph[0], fa.y - ph[1], fa.z - ph[2], fa.w - ph[3]);
            r1 = make_float4(fb.x - ph[4], fb.y - ph[5], fb.z - ph[6], fb.w - ph[7]);
        } else {
            r0 = frp[0]; r1 = frp[1];
            r0.x -= ph[0]; r0.y -= ph[1]; r0.z -= ph[2]; r0.w -= ph[3];
            r1.x -= ph[4]; r1.y -= ph[5]; r1.z -= ph[6]; r1.w -= ph[7];
        }
        frp[0] = r0; frp[1] = r1;
    }

    float lsum = 0.f;
    {
        float d;
        d = h0.x - fa.x; lsum = fmaf(d, d, lsum);
        d = h0.y - fa.y; lsum = fmaf(d, d, lsum);
        d = h0.z - fa.z; lsum = fmaf(d, d, lsum);
        d = h0.w - fa.w; lsum = fmaf(d, d, lsum);
        d = h1.x - fb.x; lsum = fmaf(d, d, lsum);
        d = h1.y - fb.y; lsum = fmaf(d, d, lsum);
        d = h1.z - fb.z; lsum = fmaf(d, d, lsum);
        d = h1.w - fb.w; lsum = fmaf(d, d, lsum);
    }

#pragma unroll
    for (int off = 32; off > 0; off >>= 1) lsum += __shfl_down(lsum, off, 64);
    if ((t & 63) == 0) red[t >> 6] = lsum;
    __syncthreads();
    if (t == 0) atomicAdd(loss_acc, red[0] + red[1] + red[2] + red[3]);
}

// ---------------------------------------------------------------- loss finalize
__global__ void final_kernel(const float* __restrict__ loss_acc, float* __restrict__ out_loss) {
    *out_loss = (*loss_acc) * (1.25f / (6.0f * (float)BCL));
}

// ---------------------------------------------------------------- launch
extern "C" void kernel_launch(void* const* d_in, const int* in_sizes, int n_in,
                              void* d_out, int out_size, void* d_ws, size_t ws_size,
                              hipStream_t stream)
{
    const float* f    = (const float*)d_in[0];
    const float* emb  = (const float*)d_in[1];
    const float* phiw = (const float*)d_in[2];
    const float* phib = (const float*)d_in[3];

    float* f_hat    = (float*)d_out;
    float* out_loss = f_hat + BCL;

    char* ws = (char*)d_ws;
    float* f_rest            = (float*)ws;                               // 4 MB
    float* e_sq              = (float*)(ws + (size_t)BCL * 4);           // 16 KB
    float* w_t               = e_sq + VDIM;                              // 48 KB
    float* loss_acc          = w_t + 4 * 96 * 32;
    unsigned long long* keys = (unsigned long long*)(ws + (size_t)BCL * 4 + 80 * 1024); // 349 KB

    init_kernel<<<dim3((NQTOT + 255) / 256), 256, 0, stream>>>(
        emb, phiw, e_sq, w_t, keys, loss_acc);

    const int lpls[6] = {0, 2, 4, 6, 8, 10};
    const int vss[6]  = {256, 256, 128, 128, 64, 16};
    const int koff[6] = {0, 32, 160, 672, 2720, 10912};
    const int pidx[6] = {0, 0, 1, 2, 3, 3};

    for (int si = 0; si < 6; ++si) {
        int lpl = lpls[si];
        int NQ  = BDIM << lpl;
        int vs  = vss[si];
        int CR  = VDIM / vs;
        const float* src = (si == 0) ? f : f_rest;
        unsigned long long* k = keys + koff[si];

        if (si >= 3) {
            int qb = (NQ + 1023) / 1024;
            vq_kernel<4><<<dim3(qb * vs), 256, 0, stream>>>(src, emb, e_sq, k, lpl, NQ, vs, CR);
        } else {
            int qb = (NQ + 255) / 256;
            vq_kernel<1><<<dim3(qb * vs), 256, 0, stream>>>(src, emb, e_sq, k, lpl, NQ, vs, CR);
        }
        fuse_kernel<<<dim3(LDIM / LT, BDIM), 256, 0, stream>>>(
            f, emb, k, w_t + (size_t)pidx[si] * 3072, phib + (size_t)pidx[si] * 32,
            f_rest, f_hat, loss_acc, lpl, si == 0, si == 5);
    }
    final_kernel<<<1, 1, 0, stream>>>(loss_acc, out_loss);
}